// Round 6
// baseline (777.745 us; speedup 1.0000x reference)
//
#include <hip/hip_runtime.h>
#include <hip/hip_bf16.h>
#include <hip/hip_fp16.h>
#include <math.h>

// T=1024 time steps, S=512 sequences, D=32 features, K=64 states (= wave width)
#define TT 1024
#define SS 512
#define DD 32
#define KK 64

#define LOG2PI_F 1.8378770664093453f

// Workspace: [0,64MB) p''[T,S,K] fp16; then mpart[8192] f32; then seq_logd[512] f32
#define PBUF_BYTES ((size_t)TT * SS * KK * 2)
#define EM_WPB 4
#define EM_BLOCKS 2048
#define NWAVES (EM_BLOCKS * EM_WPB)   // 8192

typedef _Float16 half8 __attribute__((ext_vector_type(8)));
typedef float f32x4 __attribute__((ext_vector_type(4)));

// ---------------------------------------------------------------------------
// Emission (EXACT round-4 code — passed): one wave per 64 consecutive (t,s)
// items; lane = state k. Wave-uniform base via readfirstlane; 4-item batches
// so the 6 shuffle-max rounds run as 4 independent latency chains.
__global__ __launch_bounds__(EM_WPB * 64) void emission_kernel(
    const float* __restrict__ data,      // [T,S,D]
    const float* __restrict__ means,     // [K,D]
    const float* __restrict__ covars,    // [K,D]
    __half* __restrict__ pbuf,           // [T,S,K]
    float* __restrict__ mpart)           // [NWAVES]
{
    const int k  = threadIdx.x & 63;
    const int wv = blockIdx.x * EM_WPB + (threadIdx.x >> 6);

    float w[DD], m[DD];
    float c0 = DD * LOG2PI_F;
#pragma unroll
    for (int d = 0; d < DD; ++d) {
        float c = covars[k * DD + d];
        w[d] = 1.0f / c;
        m[d] = means[k * DD + d];
        c0 += __logf(c);
    }

    const int base = __builtin_amdgcn_readfirstlane(wv) * 64;
    float macc = 0.0f;

    for (int i0 = 0; i0 < 64; i0 += 4) {
        float lp[4];
#pragma unroll
        for (int ii = 0; ii < 4; ++ii) {
            const float4* xp = (const float4*)(data + (size_t)(base + i0 + ii) * DD);
            float q0 = 0.0f, q1 = 0.0f;
#pragma unroll
            for (int d4 = 0; d4 < DD / 4; ++d4) {
                float4 x = xp[d4];
                float t0 = x.x - m[4*d4+0]; q0 = fmaf(w[4*d4+0] * t0, t0, q0);
                float t1 = x.y - m[4*d4+1]; q1 = fmaf(w[4*d4+1] * t1, t1, q1);
                float t2 = x.z - m[4*d4+2]; q0 = fmaf(w[4*d4+2] * t2, t2, q0);
                float t3 = x.w - m[4*d4+3]; q1 = fmaf(w[4*d4+3] * t3, t3, q1);
            }
            lp[ii] = -0.5f * (q0 + q1 + c0);
        }
        float mx[4] = {lp[0], lp[1], lp[2], lp[3]};
#pragma unroll
        for (int off = 32; off > 0; off >>= 1) {
#pragma unroll
            for (int ii = 0; ii < 4; ++ii)
                mx[ii] = fmaxf(mx[ii], __shfl_xor(mx[ii], off, 64));
        }
#pragma unroll
        for (int ii = 0; ii < 4; ++ii) {
            pbuf[(size_t)(base + i0 + ii) * KK + k] =
                __float2half(__expf(lp[ii] - mx[ii]));
            macc += mx[ii];   // wave-uniform
        }
    }
    if (k == 0) mpart[wv] = macc;
}

// ---------------------------------------------------------------------------
// MFMA forward recursion (round-4 structure, which PASSED; + the two fixes
// its counters demanded):
//   FIX 1: 4-deep prefetch ring for the 16 scattered 2B p'' gathers
//          (round 4's 1-step lookahead exposed ~500cyc L3 latency per step).
//   FIX 2: LDS row stride 64->72 halfs (144B, still 16B-aligned) to kill the
//          measured 261888 bank conflicts on the C->A ds_read_b128s.
// Algebra (verified round 4, absmax 3.9e-3): delayed normalization —
//   v_t = p'' (.) (y_{t-1} @ A);  z_t = v_t * corr,  corr = d_{t-2}/d_{t-1};
//   y_t = v_t * corr/d_{t-1} stored fp16;  d_t = sum(v_t)*corr (4-round
//   16-lane shuffle reduce, needed only at t+1 => off the critical path).
#define LROW 72

__global__ __launch_bounds__(64) void hmm_seq(
    const __half* __restrict__ pbuf,     // [T,S,K]
    const float* __restrict__ initial,   // [K]
    const float* __restrict__ trans,     // [K,K]
    float* __restrict__ out_alpha,       // [S,K]
    float* __restrict__ seq_logd)        // [S]
{
    const int L = threadIdx.x;
    const int sbase = blockIdx.x * 16;

    // C-layout decode: C[row=q*4+r][col=tile*16+c], c=L&15, q=L>>4
    const int c = L & 15;
    const int q = L >> 4;
    // A-frag read decode: A[m=L&15][k=f*32+(L>>4)*8+j]
    const int rA  = L & 3;
    const int qCA = (L & 15) >> 2;
    const int kb  = (L >> 4) & 1;
    const int th  = (L >> 4) >> 1;

    // B fragments of trans (fp16): B[k=(L>>4)*8+j][n=tile*16+c]
    half8 Bf[4][2];
#pragma unroll
    for (int tile = 0; tile < 4; ++tile)
#pragma unroll
        for (int h = 0; h < 2; ++h)
#pragma unroll
            for (int j = 0; j < 8; ++j)
                Bf[tile][h][j] =
                    (_Float16)trans[(h * 32 + q * 8 + j) * KK + tile * 16 + c];

    __shared__ __align__(16) _Float16 LDSH[16 * LROW];

    // p'' gather base: element (sbase+q*4+r)*KK + tile*16 + c at time t
    const __half* pb = pbuf + (size_t)(sbase + q * 4) * KK + c;
    const size_t PST = (size_t)SS * KK;

    float d1[4] = {1,1,1,1}, d2[4] = {1,1,1,1};
    float prod[4] = {1,1,1,1}, logd[4] = {0,0,0,0};

    // 4-deep prefetch ring: pr[t&3] holds p''_t
    __half pr[4][16];
#pragma unroll
    for (int u = 0; u < 4; ++u)
#pragma unroll
        for (int tile = 0; tile < 4; ++tile)
#pragma unroll
            for (int r = 0; r < 4; ++r)
                pr[u][tile * 4 + r] = pb[PST * (size_t)u + r * KK + tile * 16];

    float ini[4];
#pragma unroll
    for (int tile = 0; tile < 4; ++tile) ini[tile] = initial[tile * 16 + c];

    half8 aA0, aA1;

    for (int t4 = 0; t4 < TT / 4; ++t4) {
#pragma unroll
        for (int u = 0; u < 4; ++u) {
            const int t = 4 * t4 + u;

            // ---- v = (y_{t-1} @ A) (.) p''_t   (t=0: initial (.) p''_0) ----
            float v[4][4];
            if (t == 0) {
#pragma unroll
                for (int tile = 0; tile < 4; ++tile)
#pragma unroll
                    for (int r = 0; r < 4; ++r)
                        v[tile][r] = ini[tile] * __half2float(pr[0][tile * 4 + r]);
            } else {
                f32x4 C[4];
#pragma unroll
                for (int tile = 0; tile < 4; ++tile) {
                    f32x4 z4 = {0.0f, 0.0f, 0.0f, 0.0f};
                    z4 = __builtin_amdgcn_mfma_f32_16x16x32_f16(aA0, Bf[tile][0], z4, 0, 0, 0);
                    C[tile] = __builtin_amdgcn_mfma_f32_16x16x32_f16(aA1, Bf[tile][1], z4, 0, 0, 0);
                }
#pragma unroll
                for (int tile = 0; tile < 4; ++tile)
#pragma unroll
                    for (int r = 0; r < 4; ++r)
                        v[tile][r] = C[tile][r] * __half2float(pr[u][tile * 4 + r]);
            }

            // ---- prefetch p''_{t+4} into slot u (4 steps to land) ----
            {
                int tn = t + 4; if (tn >= TT) tn = TT - 1;   // harmless clamp
                const __half* ptn = pb + PST * (size_t)tn;
#pragma unroll
                for (int tile = 0; tile < 4; ++tile)
#pragma unroll
                    for (int r = 0; r < 4; ++r)
                        pr[u][tile * 4 + r] = ptn[r * KK + tile * 16];
            }

            // ---- scalar factors from d_{t-1}, d_{t-2} (both known) ----
            float corr[4], gsc[4];
#pragma unroll
            for (int r = 0; r < 4; ++r) {
                float rd1 = __builtin_amdgcn_rcpf(d1[r]);
                corr[r] = d2[r] * rd1;
                gsc[r]  = corr[r] * rd1;
            }

            // ---- store y_t = v*gsc (fp16), read back as A-frags ----
#pragma unroll
            for (int tile = 0; tile < 4; ++tile)
#pragma unroll
                for (int r = 0; r < 4; ++r)
                    LDSH[(tile * 4 + r) * LROW + L] = (_Float16)(v[tile][r] * gsc[r]);
            __builtin_amdgcn_wave_barrier();
            aA0 = *(const half8*)&LDSH[(th * 4 + rA) * LROW + qCA * 16 + kb * 8];
            aA1 = *(const half8*)&LDSH[((2 + th) * 4 + rA) * LROW + qCA * 16 + kb * 8];
            __builtin_amdgcn_wave_barrier();

            // ---- d_t reduce (16-lane groups; needed only at t+1) ----
            float S[4];
#pragma unroll
            for (int r = 0; r < 4; ++r)
                S[r] = (v[0][r] + v[1][r]) + (v[2][r] + v[3][r]);
#pragma unroll
            for (int msk = 1; msk < 16; msk <<= 1)
#pragma unroll
                for (int r = 0; r < 4; ++r)
                    S[r] += __shfl_xor(S[r], msk, 64);
#pragma unroll
            for (int r = 0; r < 4; ++r) {
                float dt = S[r] * corr[r];
                prod[r] *= dt;
                d2[r] = d1[r];
                d1[r] = dt;
            }
            if (u == 3) {                       // t % 4 == 3: flush logs
#pragma unroll
                for (int r = 0; r < 4; ++r) {
                    logd[r] += __logf(prod[r]);
                    prod[r] = 1.0f;
                }
            }

            if (t == TT - 1) {
                // alpha = z/d = (v*corr)/(S*corr) = v/S
#pragma unroll
                for (int tile = 0; tile < 4; ++tile)
#pragma unroll
                    for (int r = 0; r < 4; ++r)
                        out_alpha[(size_t)(sbase + q * 4 + r) * KK + tile * 16 + c] =
                            v[tile][r] / S[r];
                if (c == 0) {
#pragma unroll
                    for (int r = 0; r < 4; ++r)
                        seq_logd[sbase + q * 4 + r] = logd[r];
                }
            }
        }
    }
}

// ---------------------------------------------------------------------------
// nll = -( sum_s seq_logd[s] + sum_w mpart[w] )
__global__ __launch_bounds__(256) void finalize(
    const float* __restrict__ seq_logd, const float* __restrict__ mpart,
    float* __restrict__ out_nll)
{
    float v = 0.0f;
    for (int j = threadIdx.x; j < NWAVES; j += 256) v += mpart[j];
    for (int j = threadIdx.x; j < SS; j += 256) v += seq_logd[j];
#pragma unroll
    for (int off = 32; off > 0; off >>= 1)
        v += __shfl_xor(v, off, 64);
    __shared__ float sh[4];
    if ((threadIdx.x & 63) == 0) sh[threadIdx.x >> 6] = v;
    __syncthreads();
    if (threadIdx.x == 0) {
        double total = ((double)sh[0] + sh[1]) + ((double)sh[2] + sh[3]);
        out_nll[0] = (float)(-total);
    }
}

extern "C" void kernel_launch(void* const* d_in, const int* in_sizes, int n_in,
                              void* d_out, int out_size, void* d_ws, size_t ws_size,
                              hipStream_t stream) {
    const float* data    = (const float*)d_in[0];  // [T,S,D]
    const float* initial = (const float*)d_in[1];  // [K]
    const float* trans   = (const float*)d_in[2];  // [K,K]
    const float* means   = (const float*)d_in[3];  // [K,D]
    const float* covars  = (const float*)d_in[4];  // [K,D]

    float* out_alpha = (float*)d_out;                    // [S,K]
    float* out_nll   = (float*)d_out + (size_t)SS * KK;  // 1 float

    __half* pbuf     = (__half*)d_ws;
    float*  mpart    = (float*)((char*)d_ws + PBUF_BYTES);
    float*  seq_logd = (float*)((char*)d_ws + PBUF_BYTES + NWAVES * sizeof(float));

    emission_kernel<<<EM_BLOCKS, EM_WPB * 64, 0, stream>>>(
        data, means, covars, pbuf, mpart);
    hmm_seq<<<SS / 16, 64, 0, stream>>>(pbuf, initial, trans, out_alpha, seq_logd);
    finalize<<<1, 256, 0, stream>>>(seq_logd, mpart, out_nll);
}